// Round 2
// baseline (338.968 us; speedup 1.0000x reference)
//
#include <hip/hip_runtime.h>
#include <math.h>

// Fused Bayesian-logistic-regression sampling kernel.
// out[i,s] = sigmoid( sqrt(sum_j X_ij^2 * exp(lv_j)) * z_s + sum_j X_ij * mu_j )
//
// Layout: 16 lanes cooperate on one row (D=64 -> one float4 per lane).
// Memory-bound: 128 MB read (X) + 256 MB write (out) -> ~61 us floor @6.3TB/s.
//
// v2 changes vs. 331us baseline:
//  - persistent grid-stride groups (32768 groups x ~15 rows): weight/z preamble
//    (5 cached vec loads + 4 v_exp) hoisted out of the per-row path
//  - 1-deep software pipeline: next row's X load issued before current row's
//    reduction/sigmoid tail -> raises loads-in-flight per wave (was MLP=1)
//  - sigmoid via v_rcp_f32 (<=1 ulp) instead of 8 full-precision div sequences
//  - nontemporal loads/stores: zero-reuse streams bypass L2 thrash

typedef float f4 __attribute__((ext_vector_type(4)));

__device__ __forceinline__ float sigmoid_fast(float t) {
    // 1/(1+exp(-t)); v_rcp_f32 handles inf -> 0 so saturation is correct.
    return __builtin_amdgcn_rcpf(1.0f + __expf(-t));
}

__global__ __launch_bounds__(256) void logreg_sample_kernel(
    const float* __restrict__ X,
    const float* __restrict__ w_mu,
    const float* __restrict__ w_lv,
    const float* __restrict__ z,
    float* __restrict__ out,
    int n_rows)
{
    const int tid  = blockIdx.x * blockDim.x + threadIdx.x;
    const int grp  = tid >> 4;                       // 16 lanes per row-group
    const int l    = tid & 15;                       // lane within group
    const int ngrp = (gridDim.x * blockDim.x) >> 4;  // total row-groups

    // Row-invariant per-lane constants: hoisted out of the row loop.
    const f4 mu4 = ((const f4*)w_mu)[l];
    const f4 lv4 = ((const f4*)w_lv)[l];
    f4 ev4;
    ev4[0] = __expf(lv4[0]); ev4[1] = __expf(lv4[1]);
    ev4[2] = __expf(lv4[2]); ev4[3] = __expf(lv4[3]);
    // This lane's 8 z-samples: columns [4l, 4l+4) and [64+4l, 64+4l+4)
    const f4 z0 = ((const f4*)z)[l];
    const f4 z1 = ((const f4*)z)[16 + l];

    int row = grp;
    if (row >= n_rows) return;

    const f4* Xv = (const f4*)X;

    // Prologue load; each iteration prefetches the NEXT row before computing
    // the current one, so one 16B/lane load is always in flight per wave.
    f4 xc = __builtin_nontemporal_load(&Xv[(size_t)row * 16 + l]);

    while (row < n_rows) {
        const int nrow = row + ngrp;
        f4 xn = {0.0f, 0.0f, 0.0f, 0.0f};
        if (nrow < n_rows)
            xn = __builtin_nontemporal_load(&Xv[(size_t)nrow * 16 + l]);

        float a = xc[0] * mu4[0] + xc[1] * mu4[1]
                + xc[2] * mu4[2] + xc[3] * mu4[3];
        float b = xc[0] * xc[0] * ev4[0] + xc[1] * xc[1] * ev4[1]
                + xc[2] * xc[2] * ev4[2] + xc[3] * xc[3] * ev4[3];

        // Butterfly reduction across the 16-lane group; masks 1..8 never
        // cross the aligned 16-lane boundary; result lands in every lane.
        #pragma unroll
        for (int m = 1; m < 16; m <<= 1) {
            a += __shfl_xor(a, m, 64);
            b += __shfl_xor(b, m, 64);
        }
        const float mean = a;
        const float stdv = sqrtf(b);

        f4 o0, o1;
        o0[0] = sigmoid_fast(stdv * z0[0] + mean);
        o0[1] = sigmoid_fast(stdv * z0[1] + mean);
        o0[2] = sigmoid_fast(stdv * z0[2] + mean);
        o0[3] = sigmoid_fast(stdv * z0[3] + mean);
        o1[0] = sigmoid_fast(stdv * z1[0] + mean);
        o1[1] = sigmoid_fast(stdv * z1[1] + mean);
        o1[2] = sigmoid_fast(stdv * z1[2] + mean);
        o1[3] = sigmoid_fast(stdv * z1[3] + mean);

        // Two contiguous-256B-per-group stores: cols [4l,4l+4) and [64+4l,..).
        f4* orow = (f4*)(out + (size_t)row * 128);
        __builtin_nontemporal_store(o0, orow + l);
        __builtin_nontemporal_store(o1, orow + 16 + l);

        xc  = xn;
        row = nrow;
    }
}

extern "C" void kernel_launch(void* const* d_in, const int* in_sizes, int n_in,
                              void* d_out, int out_size, void* d_ws, size_t ws_size,
                              hipStream_t stream) {
    const float* X    = (const float*)d_in[0];
    const float* w_mu = (const float*)d_in[1];
    const float* w_lv = (const float*)d_in[2];
    const float* z    = (const float*)d_in[3];
    float* out = (float*)d_out;

    const int n_rows = in_sizes[0] / 64;          // 500000
    const int threads = 256;
    // Persistent grid: 2048 blocks = 32768 row-groups (~15 rows each),
    // grid-strided. Cap at one-group-per-row for small inputs.
    int blocks = 2048;
    long long need = ((long long)n_rows * 16 + threads - 1) / threads;
    if (need < blocks) blocks = (int)need;

    logreg_sample_kernel<<<blocks, threads, 0, stream>>>(X, w_mu, w_lv, z, out, n_rows);
}